// Round 5
// baseline (861.482 us; speedup 1.0000x reference)
//
#include <hip/hip_runtime.h>

#define HID    128
#define NTREES 8
#define DEPTH  15
#define TNODES 32767
#define VOCAB  32000
#define SMALL_TOP 4   // levels SMALL_TOP..0 run in one single-block kernel

typedef __attribute__((ext_vector_type(8))) short bfrag8;   // 8 bf16 = 4 VGPR
typedef __attribute__((ext_vector_type(4))) float facc4;    // MFMA C/D
typedef __attribute__((ext_vector_type(4))) unsigned int u32x4;

union U8 { u32x4 q; bfrag8 b; };

__device__ __forceinline__ unsigned short f2b(float x) {
  union { float f; unsigned u; } a; a.f = x;
  unsigned r = a.u + 0x7fffu + ((a.u >> 16) & 1u);   // RNE
  return (unsigned short)(r >> 16);
}
__device__ __forceinline__ float b2f(unsigned short b) {
  union { float f; unsigned u; } a; a.u = ((unsigned)b) << 16;
  return a.f;
}
__device__ __forceinline__ float fast_sigmoid(float x) {
  return __builtin_amdgcn_rcpf(1.0f + __expf(-x));
}
__device__ __forceinline__ float fast_tanh(float x) {
  return 1.0f - 2.0f * __builtin_amdgcn_rcpf(1.0f + __expf(2.0f * x));
}
// coalesced global->LDS DMA, 16B per lane; lds dest must be wave-uniform base
__device__ __forceinline__ void gl_lds16(const unsigned short* g, unsigned short* l) {
  __builtin_amdgcn_global_load_lds(
      (const __attribute__((address_space(1))) unsigned int*)g,
      (__attribute__((address_space(3))) unsigned int*)l, 16, 0, 0);
}
// swizzled child-tile fragment read: row in [0,64), slot = k*4+lgrp (16B units)
__device__ __forceinline__ bfrag8 lds_frag(const unsigned short* child_s, int row, int slot) {
  int byte = (row << 8) + ((slot ^ (row & 7)) << 4);
  return *(const bfrag8*)((const char*)child_s + byte);
}

// bf16-convert weights (transposed [N][K]) and the whole emb table.
__global__ void prep_kernel(const float* __restrict__ W_iou,
                            const float* __restrict__ U_iou,
                            const float* __restrict__ U_f_w,
                            const float* __restrict__ emb,
                            unsigned short* __restrict__ Wt,
                            unsigned short* __restrict__ Ut,
                            unsigned short* __restrict__ Uft,
                            unsigned short* __restrict__ emb_b) {
  int i = blockIdx.x * 256 + threadIdx.x;
  if (i < 384 * HID) {
    int n = i >> 7, k = i & 127;
    Wt[i] = f2b(W_iou[k * 384 + n]);
    Ut[i] = f2b(U_iou[k * 384 + n]);
  }
  if (i < HID * HID) {
    int n = i >> 7, k = i & 127;
    Uft[i] = f2b(U_f_w[k * HID + n]);
  }
  for (int j = i; j < VOCAB * HID; j += gridDim.x * 256) emb_b[j] = f2b(emb[j]);
}

// ---- leaf (level 14): LDS-free, zero barriers. 512 thr = 8 waves.
// wave w: rows 16*(w&1)..+16, cols 32*(w>>1)..+32 (full 128-B lines per wave).
__global__ __launch_bounds__(512, 6)
void leaf_kernel(const int* __restrict__ wordid, const int* __restrict__ mask,
                 const float* __restrict__ c_init,
                 const unsigned short* __restrict__ emb_b,
                 const unsigned short* __restrict__ Wt,
                 const float* __restrict__ b_iou,
                 float* __restrict__ h_out, unsigned short* __restrict__ h_b,
                 unsigned short* __restrict__ c_b) {
  const int tid = threadIdx.x, lane = tid & 63, w = tid >> 6;
  const int lrow = lane & 15, lgrp = lane >> 4;
  const int cw = w >> 1, rw = w & 1;
  int nb = gridDim.x, b = blockIdx.x;
  if ((nb & 7) == 0) { int q = nb >> 3; b = (b & 7) * q + (b >> 3); }  // XCD chunking
  const int r0 = b * 32;
  const int level = DEPTH - 1, nl = 1 << level;

  int idx; unsigned mb;
  {
    int r = r0 + rw * 16 + lrow;
    size_t gn = (size_t)(r >> level) * TNODES + (nl - 1) + (r & (nl - 1));
    int mk = mask[gn];
    idx = wordid[gn] * mk;
    mb = mk ? 0xFFFFFFFFu : 0u;
  }
  float ci[2][4];
  #pragma unroll
  for (int dt = 0; dt < 2; ++dt) {
    int d = cw * 32 + dt * 16 + lrow;
    #pragma unroll
    for (int reg = 0; reg < 4; ++reg) {
      int r = r0 + rw * 16 + 4 * lgrp + reg;
      size_t gn = (size_t)(r >> level) * TNODES + (nl - 1) + (r & (nl - 1));
      ci[dt][reg] = c_init[gn * HID + d];
    }
  }

  facc4 acc[2][3];
  #pragma unroll
  for (int dt = 0; dt < 2; ++dt)
    #pragma unroll
    for (int g = 0; g < 3; ++g)
      #pragma unroll
      for (int e = 0; e < 4; ++e) acc[dt][g][e] = 0.f;

  #pragma unroll
  for (int k = 0; k < 4; ++k) {
    U8 p; p.q = *(const u32x4*)(emb_b + (size_t)idx * HID + k * 32 + lgrp * 8);
    p.q.x &= mb; p.q.y &= mb; p.q.z &= mb; p.q.w &= mb;
    bfrag8 ae = p.b;
    #pragma unroll
    for (int g = 0; g < 3; ++g)
      #pragma unroll
      for (int dt = 0; dt < 2; ++dt) {
        int n = g * 128 + cw * 32 + dt * 16 + lrow;
        bfrag8 wf = *(const bfrag8*)(Wt + (size_t)n * HID + k * 32 + lgrp * 8);
        acc[dt][g] = __builtin_amdgcn_mfma_f32_16x16x32_bf16(ae, wf, acc[dt][g], 0, 0, 0);
      }
  }

  #pragma unroll
  for (int dt = 0; dt < 2; ++dt) {
    int d = cw * 32 + dt * 16 + lrow;
    const float bi = b_iou[d], bo = b_iou[HID + d], bu = b_iou[2 * HID + d];
    #pragma unroll
    for (int reg = 0; reg < 4; ++reg) {
      int r = r0 + rw * 16 + 4 * lgrp + reg;
      size_t gn = (size_t)(r >> level) * TNODES + (nl - 1) + (r & (nl - 1));
      float iv = acc[dt][0][reg] + bi;
      float ov = acc[dt][1][reg] + bo;
      float uv = acc[dt][2][reg] + bu;
      float cn = fmaf(fast_sigmoid(iv), fast_tanh(uv), ci[dt][reg]);
      float hn = fast_sigmoid(ov) * fast_tanh(cn);
      c_b[(size_t)r * HID + d] = f2b(cn);
      h_b[(size_t)r * HID + d] = f2b(hn);
      h_out[gn * HID + d] = hn;
    }
  }
}

// ---- one 32-node tile of a non-leaf level (shared by per-level + merged kernels)
// LDS child tile staged via global_load_lds (pre-swizzled source); 1 barrier.
template <bool CPB>   // c_prev stored bf16 (only level 13)
__device__ __forceinline__ void tile_body(
    int level, int r0,
    const int* __restrict__ wordid, const int* __restrict__ mask,
    const unsigned short* __restrict__ emb_b,
    const unsigned short* __restrict__ Wt, const unsigned short* __restrict__ Ut,
    const unsigned short* __restrict__ Uft,
    const float* __restrict__ b_iou, const float* __restrict__ U_f_b,
    const unsigned short* __restrict__ h_prev, const void* __restrict__ c_prev,
    float* __restrict__ h_out, unsigned short* __restrict__ h_b,
    float* __restrict__ c_cur,
    unsigned short* __restrict__ child_s, unsigned short* __restrict__ f_s)
{
  const int tid = threadIdx.x, lane = tid & 63, w = tid >> 6;
  const int lrow = lane & 15, lgrp = lane >> 4;
  const int cw = w >> 1, rw = w & 1;
  const int nl = 1 << level;
  const int R = NTREES << level, R2 = 2 * R;

  // ---- stage 64 child rows -> LDS, coalesced DMA; source pre-swizzled so the
  // linear LDS dest ends up XOR-swizzled (byte ^= (row&7)<<4) ----
  #pragma unroll
  for (int j = 0; j < 2; ++j) {
    int base = (2 * w + j) * 4;          // wave-uniform LDS row base (4 rows/issue)
    int row  = base + lgrp;              // per-lane source row
    int sl   = lrow ^ (row & 7);
    int cr   = 2 * r0 + row; if (cr > R2 - 1) cr = R2 - 1;
    gl_lds16(h_prev + (size_t)cr * HID + sl * 8, child_s + base * HID);
  }

  // ---- independent prefetches before the barrier ----
  int idx; unsigned mb;
  {
    int r = r0 + rw * 16 + lrow; if (r >= R) r = R - 1;
    size_t gn = (size_t)(r >> level) * TNODES + (nl - 1) + (r & (nl - 1));
    int mk = mask[gn];
    idx = wordid[gn] * mk;
    mb = mk ? 0xFFFFFFFFu : 0u;
  }
  float cp0[2][4], cp1[2][4];
  #pragma unroll
  for (int dt = 0; dt < 2; ++dt) {
    int d = cw * 32 + dt * 16 + lrow;
    #pragma unroll
    for (int reg = 0; reg < 4; ++reg) {
      int r = r0 + rw * 16 + 4 * lgrp + reg; if (r >= R) r = R - 1;
      if (CPB) {
        const unsigned short* cp = (const unsigned short*)c_prev;
        cp0[dt][reg] = b2f(cp[(size_t)(2 * r) * HID + d]);
        cp1[dt][reg] = b2f(cp[(size_t)(2 * r + 1) * HID + d]);
      } else {
        const float* cp = (const float*)c_prev;
        cp0[dt][reg] = cp[(size_t)(2 * r) * HID + d];
        cp1[dt][reg] = cp[(size_t)(2 * r + 1) * HID + d];
      }
    }
  }

  __syncthreads();   // staging complete (vmcnt drained by barrier semantics)

  // ---- f-GEMM: all 64 child rows x wave's own 32 f-cols (duplicated w/ w^1) ----
  facc4 accf[4][2];
  #pragma unroll
  for (int rt = 0; rt < 4; ++rt)
    #pragma unroll
    for (int c = 0; c < 2; ++c)
      #pragma unroll
      for (int e = 0; e < 4; ++e) accf[rt][c][e] = 0.f;
  #pragma unroll
  for (int k = 0; k < 4; ++k) {
    bfrag8 bf[2];
    #pragma unroll
    for (int c = 0; c < 2; ++c)
      bf[c] = *(const bfrag8*)(Uft + (size_t)(cw * 32 + c * 16 + lrow) * HID + k * 32 + lgrp * 8);
    #pragma unroll
    for (int rt = 0; rt < 4; ++rt) {
      bfrag8 af = lds_frag(child_s, rt * 16 + lrow, k * 4 + lgrp);
      accf[rt][0] = __builtin_amdgcn_mfma_f32_16x16x32_bf16(af, bf[0], accf[rt][0], 0, 0, 0);
      accf[rt][1] = __builtin_amdgcn_mfma_f32_16x16x32_bf16(af, bf[1], accf[rt][1], 0, 0, 0);
    }
  }
  // sigmoid -> f_s (wave-private columns; no barrier needed)
  #pragma unroll
  for (int c = 0; c < 2; ++c) {
    int d = cw * 32 + c * 16 + lrow;
    float fb = U_f_b[d];
    #pragma unroll
    for (int rt = 0; rt < 4; ++rt)
      #pragma unroll
      for (int reg = 0; reg < 4; ++reg)
        f_s[(rt * 16 + 4 * lgrp + reg) * 130 + d] = f2b(fast_sigmoid(accf[rt][c][reg] + fb));
  }

  // ---- iou GEMM: emb@Wt + ch0@Ut + ch1@Ut (children from LDS) ----
  facc4 acc[2][3];
  #pragma unroll
  for (int dt = 0; dt < 2; ++dt)
    #pragma unroll
    for (int g = 0; g < 3; ++g)
      #pragma unroll
      for (int e = 0; e < 4; ++e) acc[dt][g][e] = 0.f;

  #pragma unroll
  for (int k = 0; k < 4; ++k) {
    U8 p; p.q = *(const u32x4*)(emb_b + (size_t)idx * HID + k * 32 + lgrp * 8);
    p.q.x &= mb; p.q.y &= mb; p.q.z &= mb; p.q.w &= mb;
    bfrag8 ae = p.b;
    int ar0 = rw * 32 + 2 * lrow;
    bfrag8 a0 = lds_frag(child_s, ar0,     k * 4 + lgrp);
    bfrag8 a1 = lds_frag(child_s, ar0 + 1, k * 4 + lgrp);
    #pragma unroll
    for (int g = 0; g < 3; ++g)
      #pragma unroll
      for (int dt = 0; dt < 2; ++dt) {
        int n = g * 128 + cw * 32 + dt * 16 + lrow;
        bfrag8 wf = *(const bfrag8*)(Wt + (size_t)n * HID + k * 32 + lgrp * 8);
        bfrag8 uf = *(const bfrag8*)(Ut + (size_t)n * HID + k * 32 + lgrp * 8);
        acc[dt][g] = __builtin_amdgcn_mfma_f32_16x16x32_bf16(ae, wf, acc[dt][g], 0, 0, 0);
        acc[dt][g] = __builtin_amdgcn_mfma_f32_16x16x32_bf16(a0, uf, acc[dt][g], 0, 0, 0);
        acc[dt][g] = __builtin_amdgcn_mfma_f32_16x16x32_bf16(a1, uf, acc[dt][g], 0, 0, 0);
      }
  }

  // ---- LSTM epilogue: wave writes full 128-B lines (dt=0,1 adjacent stores) ----
  #pragma unroll
  for (int dt = 0; dt < 2; ++dt) {
    int d = cw * 32 + dt * 16 + lrow;
    const float bi = b_iou[d], bo = b_iou[HID + d], bu = b_iou[2 * HID + d];
    #pragma unroll
    for (int reg = 0; reg < 4; ++reg) {
      int m = rw * 16 + 4 * lgrp + reg;
      int r = r0 + m;
      if (r >= R) continue;
      int tree = r >> level, jj = r & (nl - 1);
      size_t gn = (size_t)tree * TNODES + (nl - 1) + jj;
      float iv = acc[dt][0][reg] + bi;
      float ov = acc[dt][1][reg] + bo;
      float uv = acc[dt][2][reg] + bu;
      float cin = b2f(f_s[(2 * m) * 130 + d]) * cp0[dt][reg]
                + b2f(f_s[(2 * m + 1) * 130 + d]) * cp1[dt][reg];
      float cn = fmaf(fast_sigmoid(iv), fast_tanh(uv), cin);
      float hn = fast_sigmoid(ov) * fast_tanh(cn);
      c_cur[(size_t)r * HID + d] = cn;
      h_b[(size_t)r * HID + d] = f2b(hn);
      h_out[gn * HID + d] = hn;
      if (gn == 0) h_out[(size_t)NTREES * TNODES * HID + d] = hn;   // h_all[0] tail
    }
  }
}

template <bool CPB>
__global__ __launch_bounds__(512, 4)
void nonleaf_kernel(int level,
                    const int* __restrict__ wordid, const int* __restrict__ mask,
                    const unsigned short* __restrict__ emb_b,
                    const unsigned short* __restrict__ Wt,
                    const unsigned short* __restrict__ Ut,
                    const unsigned short* __restrict__ Uft,
                    const float* __restrict__ b_iou, const float* __restrict__ U_f_b,
                    const unsigned short* __restrict__ h_prev, const void* __restrict__ c_prev,
                    float* __restrict__ h_out, unsigned short* __restrict__ h_b,
                    float* __restrict__ c_cur) {
  __shared__ __align__(16) unsigned short child_s[64 * HID];
  __shared__ __align__(16) unsigned short f_s[64 * 130];
  int nb = gridDim.x, b = blockIdx.x;
  if ((nb & 7) == 0) { int q = nb >> 3; b = (b & 7) * q + (b >> 3); }  // XCD chunking
  tile_body<CPB>(level, b * 32, wordid, mask, emb_b, Wt, Ut, Uft, b_iou, U_f_b,
                 h_prev, c_prev, h_out, h_b, c_cur, child_s, f_s);
}

// levels SMALL_TOP..0 in ONE single-block kernel (intra-CU barriers only)
__global__ __launch_bounds__(512, 4)
void small_kernel(const int* __restrict__ wordid, const int* __restrict__ mask,
                  const unsigned short* __restrict__ emb_b,
                  const unsigned short* __restrict__ Wt,
                  const unsigned short* __restrict__ Ut,
                  const unsigned short* __restrict__ Uft,
                  const float* __restrict__ b_iou, const float* __restrict__ U_f_b,
                  float* __restrict__ h_out,
                  unsigned short* __restrict__ hA, unsigned short* __restrict__ hB,
                  void* __restrict__ cA, void* __restrict__ cB) {
  __shared__ __align__(16) unsigned short child_s[64 * HID];
  __shared__ __align__(16) unsigned short f_s[64 * 130];
  for (int l = SMALL_TOP; l >= 0; --l) {
    const unsigned short* hp = (l & 1) ? hA : hB;
    unsigned short* hc = (l & 1) ? hB : hA;
    float* cc = (float*)((l & 1) ? cB : cA);
    const void* cp = (l & 1) ? (const void*)cA : (const void*)cB;
    int ntile = ((NTREES << l) + 31) / 32;
    for (int t = 0; t < ntile; ++t) {
      tile_body<false>(l, t * 32, wordid, mask, emb_b, Wt, Ut, Uft, b_iou, U_f_b,
                       hp, cp, h_out, hc, cc, child_s, f_s);
      __syncthreads();   // drain writes; protect child_s/f_s reuse next tile/level
    }
  }
}

extern "C" void kernel_launch(void* const* d_in, const int* in_sizes, int n_in,
                              void* d_out, int out_size, void* d_ws, size_t ws_size,
                              hipStream_t stream) {
  const int*   wordid = (const int*)d_in[0];
  const int*   mask   = (const int*)d_in[1];
  const float* c_init = (const float*)d_in[3];
  const float* emb    = (const float*)d_in[4];
  const float* W_iou  = (const float*)d_in[5];
  const float* U_iou  = (const float*)d_in[6];
  const float* b_iou  = (const float*)d_in[7];
  const float* U_f_w  = (const float*)d_in[8];
  const float* U_f_b  = (const float*)d_in[9];
  float* out = (float*)d_out;

  char* ws = (char*)d_ws;                       // total used ~126 MB (<= proven 134 MB)
  unsigned short* Wt    = (unsigned short*)(ws);                 //  98,304
  unsigned short* Ut    = (unsigned short*)(ws + 98304);         //  98,304
  unsigned short* Uft   = (unsigned short*)(ws + 196608);        //  32,768
  unsigned short* emb_b = (unsigned short*)(ws + 229376);        // 8,192,000
  char* cA = ws + 8421376;     // even-level c: bf16 at leaf (33.5MB), fp32 l<=12 (<=16.8MB)
  char* cB = ws + 41975808;    // odd-level c fp32 (max 33.5MB)
  unsigned short* hA = (unsigned short*)(ws + 75530240);   // even-level h bf16 (max 33.5MB)
  unsigned short* hB = (unsigned short*)(ws + 109084672);  // odd-level h bf16 (max 16.8MB)

  prep_kernel<<<256, 256, 0, stream>>>(W_iou, U_iou, U_f_w, emb, Wt, Ut, Uft, emb_b);

  leaf_kernel<<<(NTREES << (DEPTH - 1)) / 32, 512, 0, stream>>>(
      wordid, mask, c_init, emb_b, Wt, b_iou, out, hA, (unsigned short*)cA);

  for (int l = DEPTH - 2; l > SMALL_TOP; --l) {
    int nb = (NTREES << l) / 32;
    float* ccur = (float*)((l & 1) ? cB : cA);
    const void* cprev = (l & 1) ? (const void*)cA : (const void*)cB;
    const unsigned short* hprev = (l & 1) ? hA : hB;
    unsigned short* hcur = (l & 1) ? hB : hA;
    if (l == DEPTH - 2)
      nonleaf_kernel<true><<<nb, 512, 0, stream>>>(l, wordid, mask, emb_b, Wt, Ut, Uft,
                                                   b_iou, U_f_b, hprev, cprev, out, hcur, ccur);
    else
      nonleaf_kernel<false><<<nb, 512, 0, stream>>>(l, wordid, mask, emb_b, Wt, Ut, Uft,
                                                    b_iou, U_f_b, hprev, cprev, out, hcur, ccur);
  }

  small_kernel<<<1, 512, 0, stream>>>(wordid, mask, emb_b, Wt, Ut, Uft, b_iou, U_f_b,
                                      out, hA, hB, (void*)cA, (void*)cB);
}

// Round 6
// 636.374 us; speedup vs baseline: 1.3537x; 1.3537x over previous
//
#include <hip/hip_runtime.h>

#define HID    128
#define NTREES 8
#define DEPTH  15
#define TNODES 32767
#define VOCAB  32000

typedef __attribute__((ext_vector_type(8))) short bfrag8;   // 8 bf16 = 4 VGPR
typedef __attribute__((ext_vector_type(4))) float facc4;    // MFMA C/D
typedef __attribute__((ext_vector_type(4))) unsigned int u32x4;

union U8 { u32x4 q; bfrag8 b; };

__device__ __forceinline__ unsigned short f2b(float x) {
  union { float f; unsigned u; } a; a.f = x;
  unsigned r = a.u + 0x7fffu + ((a.u >> 16) & 1u);   // RNE
  return (unsigned short)(r >> 16);
}
__device__ __forceinline__ float b2f(unsigned short b) {
  union { float f; unsigned u; } a; a.u = ((unsigned)b) << 16;
  return a.f;
}
__device__ __forceinline__ float fast_sigmoid(float x) {
  return __builtin_amdgcn_rcpf(1.0f + __expf(-x));
}
__device__ __forceinline__ float fast_tanh(float x) {
  return 1.0f - 2.0f * __builtin_amdgcn_rcpf(1.0f + __expf(2.0f * x));
}
// coalesced global->LDS DMA, 16B per lane; lds dest must be wave-uniform base
__device__ __forceinline__ void gl_lds16(const unsigned short* g, unsigned short* l) {
  __builtin_amdgcn_global_load_lds(
      (const __attribute__((address_space(1))) unsigned int*)g,
      (__attribute__((address_space(3))) unsigned int*)l, 16, 0, 0);
}
// swizzled child-tile fragment read: row in [0,64), slot = k*4+lgrp (16B units)
__device__ __forceinline__ bfrag8 lds_frag(const unsigned short* child_s, int row, int slot) {
  int byte = (row << 8) + ((slot ^ (row & 7)) << 4);
  return *(const bfrag8*)((const char*)child_s + byte);
}

// bf16-convert weights (transposed [N][K]) and the whole emb table.
__global__ void prep_kernel(const float* __restrict__ W_iou,
                            const float* __restrict__ U_iou,
                            const float* __restrict__ U_f_w,
                            const float* __restrict__ emb,
                            unsigned short* __restrict__ Wt,
                            unsigned short* __restrict__ Ut,
                            unsigned short* __restrict__ Uft,
                            unsigned short* __restrict__ emb_b) {
  int i = blockIdx.x * 256 + threadIdx.x;
  if (i < 384 * HID) {
    int n = i >> 7, k = i & 127;
    Wt[i] = f2b(W_iou[k * 384 + n]);
    Ut[i] = f2b(U_iou[k * 384 + n]);
  }
  if (i < HID * HID) {
    int n = i >> 7, k = i & 127;
    Uft[i] = f2b(U_f_w[k * HID + n]);
  }
  for (int j = i; j < VOCAB * HID; j += gridDim.x * 256) emb_b[j] = f2b(emb[j]);
}

// ---- leaf (level 14): LDS-free, zero barriers. 512 thr = 8 waves.
// wave w: rows 16*(w&1)..+16, cols 32*(w>>1)..+32 (full 128-B lines per wave).
__global__ __launch_bounds__(512, 6)
void leaf_kernel(const int* __restrict__ wordid, const int* __restrict__ mask,
                 const float* __restrict__ c_init,
                 const unsigned short* __restrict__ emb_b,
                 const unsigned short* __restrict__ Wt,
                 const float* __restrict__ b_iou,
                 float* __restrict__ h_out, unsigned short* __restrict__ h_b,
                 unsigned short* __restrict__ c_b) {
  const int tid = threadIdx.x, lane = tid & 63, w = tid >> 6;
  const int lrow = lane & 15, lgrp = lane >> 4;
  const int cw = w >> 1, rw = w & 1;
  int nb = gridDim.x, b = blockIdx.x;
  if ((nb & 7) == 0) { int q = nb >> 3; b = (b & 7) * q + (b >> 3); }  // XCD chunking
  const int r0 = b * 32;
  const int level = DEPTH - 1, nl = 1 << level;

  int idx; unsigned mb;
  {
    int r = r0 + rw * 16 + lrow;
    size_t gn = (size_t)(r >> level) * TNODES + (nl - 1) + (r & (nl - 1));
    int mk = mask[gn];
    idx = wordid[gn] * mk;
    mb = mk ? 0xFFFFFFFFu : 0u;
  }
  float ci[2][4];
  #pragma unroll
  for (int dt = 0; dt < 2; ++dt) {
    int d = cw * 32 + dt * 16 + lrow;
    #pragma unroll
    for (int reg = 0; reg < 4; ++reg) {
      int r = r0 + rw * 16 + 4 * lgrp + reg;
      size_t gn = (size_t)(r >> level) * TNODES + (nl - 1) + (r & (nl - 1));
      ci[dt][reg] = c_init[gn * HID + d];
    }
  }

  facc4 acc[2][3];
  #pragma unroll
  for (int dt = 0; dt < 2; ++dt)
    #pragma unroll
    for (int g = 0; g < 3; ++g)
      #pragma unroll
      for (int e = 0; e < 4; ++e) acc[dt][g][e] = 0.f;

  #pragma unroll
  for (int k = 0; k < 4; ++k) {
    U8 p; p.q = *(const u32x4*)(emb_b + (size_t)idx * HID + k * 32 + lgrp * 8);
    p.q.x &= mb; p.q.y &= mb; p.q.z &= mb; p.q.w &= mb;
    bfrag8 ae = p.b;
    #pragma unroll
    for (int g = 0; g < 3; ++g)
      #pragma unroll
      for (int dt = 0; dt < 2; ++dt) {
        int n = g * 128 + cw * 32 + dt * 16 + lrow;
        bfrag8 wf = *(const bfrag8*)(Wt + (size_t)n * HID + k * 32 + lgrp * 8);
        acc[dt][g] = __builtin_amdgcn_mfma_f32_16x16x32_bf16(ae, wf, acc[dt][g], 0, 0, 0);
      }
  }

  #pragma unroll
  for (int dt = 0; dt < 2; ++dt) {
    int d = cw * 32 + dt * 16 + lrow;
    const float bi = b_iou[d], bo = b_iou[HID + d], bu = b_iou[2 * HID + d];
    #pragma unroll
    for (int reg = 0; reg < 4; ++reg) {
      int r = r0 + rw * 16 + 4 * lgrp + reg;
      size_t gn = (size_t)(r >> level) * TNODES + (nl - 1) + (r & (nl - 1));
      float iv = acc[dt][0][reg] + bi;
      float ov = acc[dt][1][reg] + bo;
      float uv = acc[dt][2][reg] + bu;
      float cn = fmaf(fast_sigmoid(iv), fast_tanh(uv), ci[dt][reg]);
      float hn = fast_sigmoid(ov) * fast_tanh(cn);
      c_b[(size_t)r * HID + d] = f2b(cn);
      h_b[(size_t)r * HID + d] = f2b(hn);
      h_out[gn * HID + d] = hn;
    }
  }
}

// ---- one 32-node tile of a non-leaf level.
// LDS child tile staged via global_load_lds (pre-swizzled source); 1 barrier.
template <bool CPB>   // c_prev stored bf16 (only level 13)
__device__ __forceinline__ void tile_body(
    int level, int r0,
    const int* __restrict__ wordid, const int* __restrict__ mask,
    const unsigned short* __restrict__ emb_b,
    const unsigned short* __restrict__ Wt, const unsigned short* __restrict__ Ut,
    const unsigned short* __restrict__ Uft,
    const float* __restrict__ b_iou, const float* __restrict__ U_f_b,
    const unsigned short* __restrict__ h_prev, const void* __restrict__ c_prev,
    float* __restrict__ h_out, unsigned short* __restrict__ h_b,
    float* __restrict__ c_cur,
    unsigned short* __restrict__ child_s, unsigned short* __restrict__ f_s)
{
  const int tid = threadIdx.x, lane = tid & 63, w = tid >> 6;
  const int lrow = lane & 15, lgrp = lane >> 4;
  const int cw = w >> 1, rw = w & 1;
  const int nl = 1 << level;
  const int R = NTREES << level, R2 = 2 * R;

  // ---- stage 64 child rows -> LDS, coalesced DMA; source pre-swizzled so the
  // linear LDS dest ends up XOR-swizzled (byte ^= (row&7)<<4) ----
  #pragma unroll
  for (int j = 0; j < 2; ++j) {
    int base = (2 * w + j) * 4;          // wave-uniform LDS row base (4 rows/issue)
    int row  = base + lgrp;              // per-lane source row
    int sl   = lrow ^ (row & 7);
    int cr   = 2 * r0 + row; if (cr > R2 - 1) cr = R2 - 1;
    gl_lds16(h_prev + (size_t)cr * HID + sl * 8, child_s + base * HID);
  }

  // ---- independent prefetches before the barrier ----
  int idx; unsigned mb;
  {
    int r = r0 + rw * 16 + lrow; if (r >= R) r = R - 1;
    size_t gn = (size_t)(r >> level) * TNODES + (nl - 1) + (r & (nl - 1));
    int mk = mask[gn];
    idx = wordid[gn] * mk;
    mb = mk ? 0xFFFFFFFFu : 0u;
  }
  float cp0[2][4], cp1[2][4];
  #pragma unroll
  for (int dt = 0; dt < 2; ++dt) {
    int d = cw * 32 + dt * 16 + lrow;
    #pragma unroll
    for (int reg = 0; reg < 4; ++reg) {
      int r = r0 + rw * 16 + 4 * lgrp + reg; if (r >= R) r = R - 1;
      if (CPB) {
        const unsigned short* cp = (const unsigned short*)c_prev;
        cp0[dt][reg] = b2f(cp[(size_t)(2 * r) * HID + d]);
        cp1[dt][reg] = b2f(cp[(size_t)(2 * r + 1) * HID + d]);
      } else {
        const float* cp = (const float*)c_prev;
        cp0[dt][reg] = cp[(size_t)(2 * r) * HID + d];
        cp1[dt][reg] = cp[(size_t)(2 * r + 1) * HID + d];
      }
    }
  }

  __syncthreads();   // staging complete (vmcnt drained by barrier semantics)

  // ---- f-GEMM: all 64 child rows x wave's own 32 f-cols (duplicated w/ w^1) ----
  facc4 accf[4][2];
  #pragma unroll
  for (int rt = 0; rt < 4; ++rt)
    #pragma unroll
    for (int c = 0; c < 2; ++c)
      #pragma unroll
      for (int e = 0; e < 4; ++e) accf[rt][c][e] = 0.f;
  #pragma unroll
  for (int k = 0; k < 4; ++k) {
    bfrag8 bf[2];
    #pragma unroll
    for (int c = 0; c < 2; ++c)
      bf[c] = *(const bfrag8*)(Uft + (size_t)(cw * 32 + c * 16 + lrow) * HID + k * 32 + lgrp * 8);
    #pragma unroll
    for (int rt = 0; rt < 4; ++rt) {
      bfrag8 af = lds_frag(child_s, rt * 16 + lrow, k * 4 + lgrp);
      accf[rt][0] = __builtin_amdgcn_mfma_f32_16x16x32_bf16(af, bf[0], accf[rt][0], 0, 0, 0);
      accf[rt][1] = __builtin_amdgcn_mfma_f32_16x16x32_bf16(af, bf[1], accf[rt][1], 0, 0, 0);
    }
  }
  // sigmoid -> f_s (wave-private columns; no barrier needed)
  #pragma unroll
  for (int c = 0; c < 2; ++c) {
    int d = cw * 32 + c * 16 + lrow;
    float fb = U_f_b[d];
    #pragma unroll
    for (int rt = 0; rt < 4; ++rt)
      #pragma unroll
      for (int reg = 0; reg < 4; ++reg)
        f_s[(rt * 16 + 4 * lgrp + reg) * 130 + d] = f2b(fast_sigmoid(accf[rt][c][reg] + fb));
  }

  // ---- iou GEMM: emb@Wt + ch0@Ut + ch1@Ut (children from LDS) ----
  facc4 acc[2][3];
  #pragma unroll
  for (int dt = 0; dt < 2; ++dt)
    #pragma unroll
    for (int g = 0; g < 3; ++g)
      #pragma unroll
      for (int e = 0; e < 4; ++e) acc[dt][g][e] = 0.f;

  #pragma unroll
  for (int k = 0; k < 4; ++k) {
    U8 p; p.q = *(const u32x4*)(emb_b + (size_t)idx * HID + k * 32 + lgrp * 8);
    p.q.x &= mb; p.q.y &= mb; p.q.z &= mb; p.q.w &= mb;
    bfrag8 ae = p.b;
    int ar0 = rw * 32 + 2 * lrow;
    bfrag8 a0 = lds_frag(child_s, ar0,     k * 4 + lgrp);
    bfrag8 a1 = lds_frag(child_s, ar0 + 1, k * 4 + lgrp);
    #pragma unroll
    for (int g = 0; g < 3; ++g)
      #pragma unroll
      for (int dt = 0; dt < 2; ++dt) {
        int n = g * 128 + cw * 32 + dt * 16 + lrow;
        bfrag8 wf = *(const bfrag8*)(Wt + (size_t)n * HID + k * 32 + lgrp * 8);
        bfrag8 uf = *(const bfrag8*)(Ut + (size_t)n * HID + k * 32 + lgrp * 8);
        acc[dt][g] = __builtin_amdgcn_mfma_f32_16x16x32_bf16(ae, wf, acc[dt][g], 0, 0, 0);
        acc[dt][g] = __builtin_amdgcn_mfma_f32_16x16x32_bf16(a0, uf, acc[dt][g], 0, 0, 0);
        acc[dt][g] = __builtin_amdgcn_mfma_f32_16x16x32_bf16(a1, uf, acc[dt][g], 0, 0, 0);
      }
  }

  // ---- LSTM epilogue: wave writes full 128-B lines (dt=0,1 adjacent stores) ----
  #pragma unroll
  for (int dt = 0; dt < 2; ++dt) {
    int d = cw * 32 + dt * 16 + lrow;
    const float bi = b_iou[d], bo = b_iou[HID + d], bu = b_iou[2 * HID + d];
    #pragma unroll
    for (int reg = 0; reg < 4; ++reg) {
      int m = rw * 16 + 4 * lgrp + reg;
      int r = r0 + m;
      if (r >= R) continue;
      int tree = r >> level, jj = r & (nl - 1);
      size_t gn = (size_t)tree * TNODES + (nl - 1) + jj;
      float iv = acc[dt][0][reg] + bi;
      float ov = acc[dt][1][reg] + bo;
      float uv = acc[dt][2][reg] + bu;
      float cin = b2f(f_s[(2 * m) * 130 + d]) * cp0[dt][reg]
                + b2f(f_s[(2 * m + 1) * 130 + d]) * cp1[dt][reg];
      float cn = fmaf(fast_sigmoid(iv), fast_tanh(uv), cin);
      float hn = fast_sigmoid(ov) * fast_tanh(cn);
      c_cur[(size_t)r * HID + d] = cn;
      h_b[(size_t)r * HID + d] = f2b(hn);
      h_out[gn * HID + d] = hn;
      if (gn == 0) h_out[(size_t)NTREES * TNODES * HID + d] = hn;   // h_all[0] tail
    }
  }
}

template <bool CPB>
__global__ __launch_bounds__(512, 4)
void nonleaf_kernel(int level,
                    const int* __restrict__ wordid, const int* __restrict__ mask,
                    const unsigned short* __restrict__ emb_b,
                    const unsigned short* __restrict__ Wt,
                    const unsigned short* __restrict__ Ut,
                    const unsigned short* __restrict__ Uft,
                    const float* __restrict__ b_iou, const float* __restrict__ U_f_b,
                    const unsigned short* __restrict__ h_prev, const void* __restrict__ c_prev,
                    float* __restrict__ h_out, unsigned short* __restrict__ h_b,
                    float* __restrict__ c_cur) {
  __shared__ __align__(16) unsigned short child_s[64 * HID];
  __shared__ __align__(16) unsigned short f_s[64 * 130];
  int nb = gridDim.x, b = blockIdx.x;
  if ((nb & 7) == 0) { int q = nb >> 3; b = (b & 7) * q + (b >> 3); }  // XCD chunking
  tile_body<CPB>(level, b * 32, wordid, mask, emb_b, Wt, Ut, Uft, b_iou, U_f_b,
                 h_prev, c_prev, h_out, h_b, c_cur, child_s, f_s);
}

extern "C" void kernel_launch(void* const* d_in, const int* in_sizes, int n_in,
                              void* d_out, int out_size, void* d_ws, size_t ws_size,
                              hipStream_t stream) {
  const int*   wordid = (const int*)d_in[0];
  const int*   mask   = (const int*)d_in[1];
  const float* c_init = (const float*)d_in[3];
  const float* emb    = (const float*)d_in[4];
  const float* W_iou  = (const float*)d_in[5];
  const float* U_iou  = (const float*)d_in[6];
  const float* b_iou  = (const float*)d_in[7];
  const float* U_f_w  = (const float*)d_in[8];
  const float* U_f_b  = (const float*)d_in[9];
  float* out = (float*)d_out;

  char* ws = (char*)d_ws;                       // total used ~126 MB (<= proven 134 MB)
  unsigned short* Wt    = (unsigned short*)(ws);                 //  98,304
  unsigned short* Ut    = (unsigned short*)(ws + 98304);         //  98,304
  unsigned short* Uft   = (unsigned short*)(ws + 196608);        //  32,768
  unsigned short* emb_b = (unsigned short*)(ws + 229376);        // 8,192,000
  char* cA = ws + 8421376;     // even-level c: bf16 at leaf (33.5MB), fp32 l<=12 (<=16.8MB)
  char* cB = ws + 41975808;    // odd-level c fp32 (max 33.5MB)
  unsigned short* hA = (unsigned short*)(ws + 75530240);   // even-level h bf16 (max 33.5MB)
  unsigned short* hB = (unsigned short*)(ws + 109084672);  // odd-level h bf16 (max 16.8MB)

  prep_kernel<<<256, 256, 0, stream>>>(W_iou, U_iou, U_f_w, emb, Wt, Ut, Uft, emb_b);

  leaf_kernel<<<(NTREES << (DEPTH - 1)) / 32, 512, 0, stream>>>(
      wordid, mask, c_init, emb_b, Wt, b_iou, out, hA, (unsigned short*)cA);

  for (int l = DEPTH - 2; l >= 0; --l) {
    int nb = ((NTREES << l) + 31) / 32;
    float* ccur = (float*)((l & 1) ? cB : cA);
    const void* cprev = (l & 1) ? (const void*)cA : (const void*)cB;
    const unsigned short* hprev = (l & 1) ? hA : hB;
    unsigned short* hcur = (l & 1) ? hB : hA;
    if (l == DEPTH - 2)
      nonleaf_kernel<true><<<nb, 512, 0, stream>>>(l, wordid, mask, emb_b, Wt, Ut, Uft,
                                                   b_iou, U_f_b, hprev, cprev, out, hcur, ccur);
    else
      nonleaf_kernel<false><<<nb, 512, 0, stream>>>(l, wordid, mask, emb_b, Wt, Ut, Uft,
                                                    b_iou, U_f_b, hprev, cprev, out, hcur, ccur);
  }
}